// Round 9
// baseline (243.044 us; speedup 1.0000x reference)
//
#include <hip/hip_runtime.h>

// GraphSAGE 2-layer + linear head, N=50000, E=600000, C=128 everywhere.
// R8: REVERT fp8 (measured +7us, absmax 0.055: bytes/instr/line halving all
//     bought 0 in the aggregate => reuse is served by the L3 random path).
//     NEW: XCD-sliced aggregate — 4 channel-slices of 32ch (64B); slice =
//     blockIdx&3 and XCD = bid%8 (round-robin) => each XCD's L2 caches only
//     its 3.2MB slice of the 12.8MB table; the ~12x per-row reuse becomes
//     per-XCD L2 hits instead of L3 round-trips. Wave = 16 nodes x 4 lanes
//     (quad reads contiguous 64B/edge), serial edge loop w/ x4 prefetch.

typedef _Float16 f16;
typedef __attribute__((ext_vector_type(4))) _Float16 f16x4;
typedef __attribute__((ext_vector_type(8))) _Float16 f16x8;
typedef __attribute__((ext_vector_type(4))) float f32x4;

#define RNB 128   // radix blocks (256 bins x 128 = 32768 scan entries)

// ---- prep: [0,cb) convert x -> f16 | [cb,cb+wb) weights | rest: radix hist
// weights k-chunked transposed, 3 tables contiguous (32768 f16 each):
// wt[w][(chunk*128 + n)*8 + j] = W_w[k=chunk*8+j][n], W = [WA;WB] stacked.
__global__ void prep_kernel(const float* __restrict__ x, f16* __restrict__ xh, int n4,
                            const int* __restrict__ ei, int* __restrict__ ghist, int E,
                            const float* __restrict__ W1l, const float* __restrict__ W1r,
                            const float* __restrict__ W2l, const float* __restrict__ W2r,
                            const float* __restrict__ Wlin, f16* __restrict__ wt,
                            int cb, int wb) {
  int b = blockIdx.x;
  if (b < cb) {
    int i = b * 256 + threadIdx.x;
    if (i < n4) {
      const float4 v = ((const float4*)x)[i];
      f16x4 h = { (f16)v.x, (f16)v.y, (f16)v.z, (f16)v.w };
      ((f16x4*)xh)[i] = h;
    }
  } else if (b < cb + wb) {
    int tid = (b - cb) * 256 + threadIdx.x;   // 0 .. 3*32768
    int w = tid >> 15, idx = tid & 32767;
    int j = idx & 7, n = (idx >> 3) & 127, chunk = idx >> 10;
    int k = chunk * 8 + j;
    float v;
    if (w == 0) v = (k < 128) ? W1l[k * 128 + n] : W1r[(k - 128) * 128 + n];
    else if (w == 1) v = (k < 128) ? W2l[k * 128 + n] : W2r[(k - 128) * 128 + n];
    else v = Wlin[k * 128 + n];
    wt[tid] = (f16)v;
  } else {
    __shared__ int h[256];
    int tid = threadIdx.x, rb = b - cb - wb;   // 0..RNB-1
    h[tid] = 0;
    __syncthreads();
    int per = (E + RNB - 1) / RNB;
    int s = rb * per, e = s + per; if (e > E) e = E;
    for (int i = s + tid; i < e; i += 256) atomicAdd(&h[ei[E + i] >> 8], 1);
    __syncthreads();
    ghist[tid * RNB + rb] = h[tid];
  }
}

// exclusive scan, 1024-elem chunks per block (Hillis-Steele, ping-pong LDS)
__global__ void scan_block_kernel(const int* __restrict__ in, int* __restrict__ out,
                                  int* __restrict__ sums, int n) {
  __shared__ int s[2][1024];
  int t = threadIdx.x;
  int gid = blockIdx.x * 1024 + t;
  int v = (gid < n) ? in[gid] : 0;
  int cur = 0;
  s[0][t] = v;
  __syncthreads();
  for (int ofs = 1; ofs < 1024; ofs <<= 1) {
    int nv = s[cur][t] + ((t >= ofs) ? s[cur][t - ofs] : 0);
    s[cur ^ 1][t] = nv;
    cur ^= 1;
    __syncthreads();
  }
  if (gid < n) out[gid] = s[cur][t] - v;      // exclusive within block
  if (t == 1023) sums[blockIdx.x] = s[cur][1023];
}

// inline exclusive prefix of the 32 chunk sums into LDS pf[32]
__device__ inline void sums_prefix(const int* sums, int* pf) {
  int t = threadIdx.x;
  if (t < 32) {
    int v = sums[t];
    int incl = v;
#pragma unroll
    for (int ofs = 1; ofs < 32; ofs <<= 1) {
      int u = __shfl_up(incl, ofs);
      if (t >= ofs) incl += u;
    }
    pf[t] = incl - v;
  }
}

// deterministic scatter into per-(block,bin) ranges; LDS cursors only.
__global__ void radix_scatter(const int* __restrict__ ei, const int* __restrict__ sg,
                              const int* __restrict__ sums, int2* __restrict__ tmp, int E) {
  __shared__ int cur[256];
  __shared__ int pf[32];
  int tid = threadIdx.x, b = blockIdx.x;
  sums_prefix(sums, pf);
  __syncthreads();
  cur[tid] = sg[tid * RNB + b] + pf[tid >> 3];
  __syncthreads();
  int per = (E + RNB - 1) / RNB;
  int s = b * per, e = s + per; if (e > E) e = E;
  for (int i = s + tid; i < e; i += 256) {
    int d = ei[E + i], sr = ei[i];
    int pos = atomicAdd(&cur[d >> 8], 1);     // LDS atomic
    tmp[pos] = make_int2(d, sr);
  }
}

// one block per high-byte bucket: LDS low-byte hist + scan -> off[] + srcs.
__global__ void radix_bucket(const int2* __restrict__ tmp, const int* __restrict__ sg,
                             const int* __restrict__ sums, int* __restrict__ srcs,
                             int* __restrict__ off, int N, int E, int HB) {
  __shared__ int h[256], sc[256], cur[256];
  __shared__ int pf[32];
  int tid = threadIdx.x, hb = blockIdx.x;
  sums_prefix(sums, pf);
  __syncthreads();
  int start = sg[hb * RNB] + pf[hb >> 3];
  int end = (hb + 1 < HB) ? (sg[(hb + 1) * RNB] + pf[(hb + 1) >> 3]) : E;
  h[tid] = 0;
  __syncthreads();
  for (int i = start + tid; i < end; i += 256) atomicAdd(&h[tmp[i].x & 255], 1);
  __syncthreads();
  sc[tid] = h[tid];
  __syncthreads();
  for (int o = 1; o < 256; o <<= 1) {
    int u = (tid >= o) ? sc[tid - o] : 0;
    __syncthreads();
    sc[tid] += u;
    __syncthreads();
  }
  int excl = sc[tid] - h[tid];
  int v = (hb << 8) + tid;
  if (v < N) off[v] = start + excl;
  if (hb == 0 && tid == 0) off[N] = E;
  cur[tid] = start + excl;
  __syncthreads();
  for (int i = start + tid; i < end; i += 256) {
    int2 p = tmp[i];
    int pos = atomicAdd(&cur[p.x & 255], 1);  // LDS atomic
    srcs[pos] = p.y;
  }
}

// XCD-sliced aggregate: slice s = blockIdx&3 covers channels [s*32, s*32+32)
// (64 B of each 256 B feature row). Round-robin XCD = bid%8 means XCD x only
// ever sees slice x&3 => its L2 caches that 3.2 MB slice; edge reuse = L2 hits.
// block = 256 thr = 4 waves; wave = 16 nodes; lane = node(lane>>2) x q(lane&3).
// quad reads one contiguous 64 B segment per edge; serial edge loop to
// wave-max degree, x4 unrolled (4 idx + 4 gathers in flight); 8xf32 accum.
__global__ void aggregate_slice_kernel(const f16* __restrict__ feat,
                                       const int* __restrict__ off,
                                       const int* __restrict__ srcs,
                                       f16* __restrict__ meanf, int n) {
  int s = blockIdx.x & 3;
  int lane = threadIdx.x & 63;
  int node = (blockIdx.x >> 2) * 64 + (threadIdx.x >> 6) * 16 + (lane >> 2);
  int q = lane & 3;
  int nc = node < n ? node : n - 1;
  int beg = off[nc], end = off[nc + 1];
  int deg = end - beg;
  int maxd = deg;
#pragma unroll
  for (int ofs = 1; ofs < 64; ofs <<= 1) {
    int o = __shfl_xor(maxd, ofs);
    maxd = o > maxd ? o : maxd;
  }
  const f16* fs = feat + s * 32 + q * 8;
  float acc[8] = {};
  for (int r = 0; r < maxd; r += 4) {
    int i0 = (r + 0 < deg) ? srcs[beg + r + 0] : 0;
    int i1 = (r + 1 < deg) ? srcs[beg + r + 1] : 0;
    int i2 = (r + 2 < deg) ? srcs[beg + r + 2] : 0;
    int i3 = (r + 3 < deg) ? srcs[beg + r + 3] : 0;
    f16x8 g0 = *(const f16x8*)(fs + (size_t)i0 * 128);
    f16x8 g1 = *(const f16x8*)(fs + (size_t)i1 * 128);
    f16x8 g2 = *(const f16x8*)(fs + (size_t)i2 * 128);
    f16x8 g3 = *(const f16x8*)(fs + (size_t)i3 * 128);
    if (r + 0 < deg) {
#pragma unroll
      for (int j = 0; j < 8; ++j) acc[j] += (float)g0[j];
    }
    if (r + 1 < deg) {
#pragma unroll
      for (int j = 0; j < 8; ++j) acc[j] += (float)g1[j];
    }
    if (r + 2 < deg) {
#pragma unroll
      for (int j = 0; j < 8; ++j) acc[j] += (float)g2[j];
    }
    if (r + 3 < deg) {
#pragma unroll
      for (int j = 0; j < 8; ++j) acc[j] += (float)g3[j];
    }
  }
  if (node < n) {
    float inv = 1.0f / fmaxf((float)deg, 1.0f);
    f16x8 o;
#pragma unroll
    for (int j = 0; j < 8; ++j) o[j] = (f16)(acc[j] * inv);
    *(f16x8*)(meanf + (size_t)node * 128 + s * 32 + q * 8) = o;
  }
}

// GEMM v2 (R3): Y[M,128] = act([U|V][M,256] @ W + bias); Wt k-chunked in LDS.
// block = 256 = 4 waves; wave computes 32 rows x 128 cols (128 rows/block).
template <bool RELU, bool OUT16>
__global__ __launch_bounds__(256, 2) void gemm_kernel(
    const f16* __restrict__ U, const f16* __restrict__ V, const f16* __restrict__ Wt,
    const float* __restrict__ bias, void* __restrict__ outp, int M) {
  __shared__ f16 ldsb[32768];   // 64 KB
  int tid = threadIdx.x;
  int wave = tid >> 6, lane = tid & 63;
  int quad = lane >> 4, n15 = lane & 15;
  int m0 = blockIdx.x * 128 + wave * 32;
  int kq = quad * 8;

  f16x8 a[2][8];
#pragma unroll
  for (int r = 0; r < 2; ++r) {
    int row = m0 + r * 16 + n15;
    int rowc = row < M ? row : M - 1;   // clamp tail loads (stores guarded)
    const f16* bu = U + (size_t)rowc * 128 + kq;
    const f16* bv = V + (size_t)rowc * 128 + kq;
#pragma unroll
    for (int kk = 0; kk < 4; ++kk) a[r][kk] = *(const f16x8*)(bu + kk * 32);
#pragma unroll
    for (int kk = 4; kk < 8; ++kk) a[r][kk] = *(const f16x8*)(bv + (kk - 4) * 32);
  }

#pragma unroll
  for (int it = 0; it < 16; ++it) {
    int idx = it * 256 + tid;
    ((f16x8*)ldsb)[idx] = ((const f16x8*)Wt)[idx];
  }
  __syncthreads();

  f32x4 acc[2][8] = {};
#pragma unroll
  for (int kk = 0; kk < 8; ++kk) {
#pragma unroll
    for (int t = 0; t < 8; ++t) {
      f16x8 b = ((const f16x8*)ldsb)[(kk * 4 + quad) * 128 + t * 16 + n15];
#pragma unroll
      for (int r = 0; r < 2; ++r)
        acc[r][t] = __builtin_amdgcn_mfma_f32_16x16x32_f16(a[r][kk], b, acc[r][t], 0, 0, 0);
    }
  }

  int rbase0 = m0 + quad * 4;
#pragma unroll
  for (int t = 0; t < 8; ++t) {
    float bv = bias[t * 16 + n15];
#pragma unroll
    for (int r = 0; r < 2; ++r) {
#pragma unroll
      for (int i = 0; i < 4; ++i) {
        int row = rbase0 + r * 16 + i;
        if (row < M) {
          float v = acc[r][t][i] + bv;
          if (RELU) v = fmaxf(v, 0.f);
          size_t idx = (size_t)row * 128 + t * 16 + n15;
          if (OUT16) ((f16*)outp)[idx] = (f16)v;
          else       ((float*)outp)[idx] = v;
        }
      }
    }
  }
}

extern "C" void kernel_launch(void* const* d_in, const int* in_sizes, int n_in,
                              void* d_out, int out_size, void* d_ws, size_t ws_size,
                              hipStream_t stream) {
  (void)n_in; (void)out_size; (void)ws_size;
  const float* x    = (const float*)d_in[0];
  const int*   ei   = (const int*)d_in[1];
  const float* W1l  = (const float*)d_in[2];
  const float* b1l  = (const float*)d_in[3];
  const float* W1r  = (const float*)d_in[4];
  const float* W2l  = (const float*)d_in[5];
  const float* b2l  = (const float*)d_in[6];
  const float* W2r  = (const float*)d_in[7];
  const float* Wlin = (const float*)d_in[8];
  const float* blin = (const float*)d_in[9];
  const int N = in_sizes[0] / 128;
  const int E = in_sizes[1] / 2;

  char* ws = (char*)d_ws;
  size_t o = 0;
  auto alloc = [&](size_t bytes) {
    char* p = ws + o;
    o = (o + bytes + 255) & ~(size_t)255;
    return p;
  };
  f16*  xh   = (f16*)alloc((size_t)N * 128 * 2);
  f16*  x1h  = (f16*)alloc((size_t)N * 128 * 2);
  f16*  x2h  = (f16*)alloc((size_t)N * 128 * 2);
  f16*  mh   = (f16*)alloc((size_t)N * 128 * 2);
  f16*  wt   = (f16*)alloc((size_t)3 * 32768 * 2);   // wt1|wt2|wt3 contiguous
  int*  off  = (int*)alloc(((size_t)N + 1) * 4);
  int*  srcs = (int*)alloc((size_t)E * 4);
  int2* tmp  = (int2*)alloc((size_t)E * 8);
  int*  ghist= (int*)alloc(256 * RNB * 4);
  int*  sg   = (int*)alloc(256 * RNB * 4);
  int*  sums = (int*)alloc(64 * 4);
  f16* wt1 = wt, *wt2 = wt + 32768, *wt3 = wt + 65536;

  const int n4 = N * 128 / 4;
  const int cb = (n4 + 255) / 256;           // convert blocks
  const int wb = (3 * 32768) / 256;          // weight blocks (384)
  const int HB = (N + 255) / 256;            // high-byte buckets (196)
  const int SN = 256 * RNB;                  // scan length 32768
  const int snb = SN / 1024;                 // 32 scan blocks

  // prep (convert + weights + radix hist)
  prep_kernel<<<cb + wb + RNB, 256, 0, stream>>>(x, xh, n4, ei, ghist, E,
                                                 W1l, W1r, W2l, W2r, Wlin, wt, cb, wb);
  // CSR build (atomic-free; chunk prefixes folded into consumers)
  scan_block_kernel<<<snb, 1024, 0, stream>>>(ghist, sg, sums, SN);
  radix_scatter<<<RNB, 256, 0, stream>>>(ei, sg, sums, tmp, E);
  radix_bucket<<<HB, 256, 0, stream>>>(tmp, sg, sums, srcs, off, N, E, HB);

  const int aggBlocks  = ((N + 63) / 64) * 4;   // 64 nodes/block x 4 slices
  const int gemmBlocks = (N + 127) / 128;       // 128 rows/block

  // layer 1: x1 = relu(mean(x) @ W1_l + x @ W1_r + b1)
  aggregate_slice_kernel<<<aggBlocks, 256, 0, stream>>>(xh, off, srcs, mh, N);
  gemm_kernel<true, true><<<gemmBlocks, 256, 0, stream>>>(mh, xh, wt1, b1l, x1h, N);
  // layer 2: x2 = relu(mean(x1) @ W2_l + x1 @ W2_r + b2)
  aggregate_slice_kernel<<<aggBlocks, 256, 0, stream>>>(x1h, off, srcs, mh, N);
  gemm_kernel<true, true><<<gemmBlocks, 256, 0, stream>>>(mh, x1h, wt2, b2l, x2h, N);
  // head: out = [x1|x2] @ W_lin + b_lin   (fp32 out)
  gemm_kernel<false, false><<<gemmBlocks, 256, 0, stream>>>(x1h, x2h, wt3, blin, d_out, N);
}

// Round 10
// 226.833 us; speedup vs baseline: 1.0715x; 1.0715x over previous
//
#include <hip/hip_runtime.h>

// GraphSAGE 2-layer + linear head, N=50000, E=600000, C=128 everywhere.
// R9: best-of-measured assembly. REVERT slice-agg (+14..20 measured) back to
//     R3 f16 prefetch-all agg; keep folded prep(+hist), inline sums-prefix,
//     v2 64KB gemm (-4 vs col-split). NEW: radix tmp packed to 32 bits
//     ((src<<8)|dst.low8, valid for N<2^24) — halves intermediate traffic.
//     Failed-theory ledger for agg: ILP-depth neutral, fp8 bytes neutral,
//     XCD-slice negative => stop betting on agg models without per-kernel data.

typedef _Float16 f16;
typedef unsigned int u32;
typedef __attribute__((ext_vector_type(4))) _Float16 f16x4;
typedef __attribute__((ext_vector_type(8))) _Float16 f16x8;
typedef __attribute__((ext_vector_type(4))) float f32x4;

#define RNB 128   // radix blocks (256 bins x 128 = 32768 scan entries)

// ---- prep: [0,cb) convert x -> f16 | [cb,cb+wb) weights | rest: radix hist
// weights k-chunked transposed, 3 tables contiguous (32768 f16 each):
// wt[w][(chunk*128 + n)*8 + j] = W_w[k=chunk*8+j][n], W = [WA;WB] stacked.
__global__ void prep_kernel(const float* __restrict__ x, f16* __restrict__ xh, int n4,
                            const int* __restrict__ ei, int* __restrict__ ghist, int E,
                            const float* __restrict__ W1l, const float* __restrict__ W1r,
                            const float* __restrict__ W2l, const float* __restrict__ W2r,
                            const float* __restrict__ Wlin, f16* __restrict__ wt,
                            int cb, int wb) {
  int b = blockIdx.x;
  if (b < cb) {
    int i = b * 256 + threadIdx.x;
    if (i < n4) {
      const float4 v = ((const float4*)x)[i];
      f16x4 h = { (f16)v.x, (f16)v.y, (f16)v.z, (f16)v.w };
      ((f16x4*)xh)[i] = h;
    }
  } else if (b < cb + wb) {
    int tid = (b - cb) * 256 + threadIdx.x;   // 0 .. 3*32768
    int w = tid >> 15, idx = tid & 32767;
    int j = idx & 7, n = (idx >> 3) & 127, chunk = idx >> 10;
    int k = chunk * 8 + j;
    float v;
    if (w == 0) v = (k < 128) ? W1l[k * 128 + n] : W1r[(k - 128) * 128 + n];
    else if (w == 1) v = (k < 128) ? W2l[k * 128 + n] : W2r[(k - 128) * 128 + n];
    else v = Wlin[k * 128 + n];
    wt[tid] = (f16)v;
  } else {
    __shared__ int h[256];
    int tid = threadIdx.x, rb = b - cb - wb;   // 0..RNB-1
    h[tid] = 0;
    __syncthreads();
    int per = (E + RNB - 1) / RNB;
    int s = rb * per, e = s + per; if (e > E) e = E;
    for (int i = s + tid; i < e; i += 256) atomicAdd(&h[ei[E + i] >> 8], 1);
    __syncthreads();
    ghist[tid * RNB + rb] = h[tid];
  }
}

// exclusive scan, 1024-elem chunks per block (Hillis-Steele, ping-pong LDS)
__global__ void scan_block_kernel(const int* __restrict__ in, int* __restrict__ out,
                                  int* __restrict__ sums, int n) {
  __shared__ int s[2][1024];
  int t = threadIdx.x;
  int gid = blockIdx.x * 1024 + t;
  int v = (gid < n) ? in[gid] : 0;
  int cur = 0;
  s[0][t] = v;
  __syncthreads();
  for (int ofs = 1; ofs < 1024; ofs <<= 1) {
    int nv = s[cur][t] + ((t >= ofs) ? s[cur][t - ofs] : 0);
    s[cur ^ 1][t] = nv;
    cur ^= 1;
    __syncthreads();
  }
  if (gid < n) out[gid] = s[cur][t] - v;      // exclusive within block
  if (t == 1023) sums[blockIdx.x] = s[cur][1023];
}

// inline exclusive prefix of the 32 chunk sums into LDS pf[32]
__device__ inline void sums_prefix(const int* sums, int* pf) {
  int t = threadIdx.x;
  if (t < 32) {
    int v = sums[t];
    int incl = v;
#pragma unroll
    for (int ofs = 1; ofs < 32; ofs <<= 1) {
      int u = __shfl_up(incl, ofs);
      if (t >= ofs) incl += u;
    }
    pf[t] = incl - v;
  }
}

// deterministic scatter into per-(block,bin) ranges; LDS cursors only.
// tmp entry = (src<<8) | (dst & 255)  -- 32-bit, requires src < 2^24.
__global__ void radix_scatter(const int* __restrict__ ei, const int* __restrict__ sg,
                              const int* __restrict__ sums, u32* __restrict__ tmp, int E) {
  __shared__ int cur[256];
  __shared__ int pf[32];
  int tid = threadIdx.x, b = blockIdx.x;
  sums_prefix(sums, pf);
  __syncthreads();
  cur[tid] = sg[tid * RNB + b] + pf[tid >> 3];
  __syncthreads();
  int per = (E + RNB - 1) / RNB;
  int s = b * per, e = s + per; if (e > E) e = E;
  for (int i = s + tid; i < e; i += 256) {
    int d = ei[E + i], sr = ei[i];
    int pos = atomicAdd(&cur[d >> 8], 1);     // LDS atomic
    tmp[pos] = ((u32)sr << 8) | (u32)(d & 255);
  }
}

// one block per high-byte bucket: LDS low-byte hist + scan -> off[] + srcs.
__global__ void radix_bucket(const u32* __restrict__ tmp, const int* __restrict__ sg,
                             const int* __restrict__ sums, int* __restrict__ srcs,
                             int* __restrict__ off, int N, int E, int HB) {
  __shared__ int h[256], sc[256], cur[256];
  __shared__ int pf[32];
  int tid = threadIdx.x, hb = blockIdx.x;
  sums_prefix(sums, pf);
  __syncthreads();
  int start = sg[hb * RNB] + pf[hb >> 3];
  int end = (hb + 1 < HB) ? (sg[(hb + 1) * RNB] + pf[(hb + 1) >> 3]) : E;
  h[tid] = 0;
  __syncthreads();
  for (int i = start + tid; i < end; i += 256) atomicAdd(&h[tmp[i] & 255u], 1);
  __syncthreads();
  sc[tid] = h[tid];
  __syncthreads();
  for (int o = 1; o < 256; o <<= 1) {
    int u = (tid >= o) ? sc[tid - o] : 0;
    __syncthreads();
    sc[tid] += u;
    __syncthreads();
  }
  int excl = sc[tid] - h[tid];
  int v = (hb << 8) + tid;
  if (v < N) off[v] = start + excl;
  if (hb == 0 && tid == 0) off[N] = E;
  cur[tid] = start + excl;
  __syncthreads();
  for (int i = start + tid; i < end; i += 256) {
    u32 p = tmp[i];
    int pos = atomicAdd(&cur[p & 255u], 1);   // LDS atomic
    srcs[pos] = (int)(p >> 8);
  }
}

// agg v3 (R3, best measured): wave = 2 nodes; lane = slot(sub) x chgroup(n15).
// Prefetch up to 24 edge indices/node, then all gathers, single drain,
// fp32 accum, cross-slot shfl reduce, f16 mean out.
#define AGG_R 6
__global__ void aggregate_kernel(const f16* __restrict__ feat, const int* __restrict__ off,
                                 const int* __restrict__ srcs, f16* __restrict__ meanf, int n) {
  int pair = (int)((blockIdx.x * blockDim.x + threadIdx.x) >> 6);
  int w0 = pair * 2;
  if (w0 >= n) return;
  int w1 = w0 + 1;
  int lane = threadIdx.x & 63;
  int sub = lane >> 4, n15 = lane & 15;
  int beg0 = off[w0], end0 = off[w0 + 1];
  int beg1 = end0;                              // CSR contiguity
  int end1 = (w1 < n) ? off[w1 + 1] : end0;
  int deg0 = end0 - beg0, deg1 = end1 - beg1;

  int s0[AGG_R], s1[AGG_R];
  bool v0[AGG_R], v1[AGG_R];
#pragma unroll
  for (int k = 0; k < AGG_R; ++k) {
    int p = 4 * k + sub;
    v0[k] = p < deg0;  s0[k] = v0[k] ? srcs[beg0 + p] : 0;
    v1[k] = p < deg1;  s1[k] = v1[k] ? srcs[beg1 + p] : 0;
  }
  f16x8 g0[AGG_R], g1[AGG_R];
#pragma unroll
  for (int k = 0; k < AGG_R; ++k) {
    if (v0[k]) g0[k] = *(const f16x8*)(feat + (size_t)s0[k] * 128 + n15 * 8);
    if (v1[k]) g1[k] = *(const f16x8*)(feat + (size_t)s1[k] * 128 + n15 * 8);
  }
  float acc0[8] = {}, acc1[8] = {};
#pragma unroll
  for (int k = 0; k < AGG_R; ++k) {
    if (v0[k]) {
#pragma unroll
      for (int j = 0; j < 8; ++j) acc0[j] += (float)g0[k][j];
    }
    if (v1[k]) {
#pragma unroll
      for (int j = 0; j < 8; ++j) acc1[j] += (float)g1[k][j];
    }
  }
  for (int e = beg0 + 4 * AGG_R; e < end0; e += 4) {   // rare deg>24 tail
    if (sub < end0 - e) {
      int s = srcs[e + sub];
      f16x8 g = *(const f16x8*)(feat + (size_t)s * 128 + n15 * 8);
#pragma unroll
      for (int j = 0; j < 8; ++j) acc0[j] += (float)g[j];
    }
  }
  for (int e = beg1 + 4 * AGG_R; e < end1; e += 4) {
    if (sub < end1 - e) {
      int s = srcs[e + sub];
      f16x8 g = *(const f16x8*)(feat + (size_t)s * 128 + n15 * 8);
#pragma unroll
      for (int j = 0; j < 8; ++j) acc1[j] += (float)g[j];
    }
  }
#pragma unroll
  for (int j = 0; j < 8; ++j) {
    acc0[j] += __shfl_xor(acc0[j], 16);
    acc0[j] += __shfl_xor(acc0[j], 32);
    acc1[j] += __shfl_xor(acc1[j], 16);
    acc1[j] += __shfl_xor(acc1[j], 32);
  }
  if (sub == 0) {
    float inv = 1.0f / fmaxf((float)deg0, 1.0f);
    f16x8 o;
#pragma unroll
    for (int j = 0; j < 8; ++j) o[j] = (f16)(acc0[j] * inv);
    *(f16x8*)(meanf + (size_t)w0 * 128 + n15 * 8) = o;
  } else if (sub == 1 && w1 < n) {
    float inv = 1.0f / fmaxf((float)deg1, 1.0f);
    f16x8 o;
#pragma unroll
    for (int j = 0; j < 8; ++j) o[j] = (f16)(acc1[j] * inv);
    *(f16x8*)(meanf + (size_t)w1 * 128 + n15 * 8) = o;
  }
}

// GEMM v2 (best measured): Y[M,128] = act([U|V][M,256] @ W + bias);
// Wt k-chunked in 64KB LDS; 4 waves; wave = 32 rows x 128 cols.
template <bool RELU, bool OUT16>
__global__ __launch_bounds__(256, 2) void gemm_kernel(
    const f16* __restrict__ U, const f16* __restrict__ V, const f16* __restrict__ Wt,
    const float* __restrict__ bias, void* __restrict__ outp, int M) {
  __shared__ f16 ldsb[32768];   // 64 KB
  int tid = threadIdx.x;
  int wave = tid >> 6, lane = tid & 63;
  int quad = lane >> 4, n15 = lane & 15;
  int m0 = blockIdx.x * 128 + wave * 32;
  int kq = quad * 8;

  f16x8 a[2][8];
#pragma unroll
  for (int r = 0; r < 2; ++r) {
    int row = m0 + r * 16 + n15;
    int rowc = row < M ? row : M - 1;   // clamp tail loads (stores guarded)
    const f16* bu = U + (size_t)rowc * 128 + kq;
    const f16* bv = V + (size_t)rowc * 128 + kq;
#pragma unroll
    for (int kk = 0; kk < 4; ++kk) a[r][kk] = *(const f16x8*)(bu + kk * 32);
#pragma unroll
    for (int kk = 4; kk < 8; ++kk) a[r][kk] = *(const f16x8*)(bv + (kk - 4) * 32);
  }

#pragma unroll
  for (int it = 0; it < 16; ++it) {
    int idx = it * 256 + tid;
    ((f16x8*)ldsb)[idx] = ((const f16x8*)Wt)[idx];
  }
  __syncthreads();

  f32x4 acc[2][8] = {};
#pragma unroll
  for (int kk = 0; kk < 8; ++kk) {
#pragma unroll
    for (int t = 0; t < 8; ++t) {
      f16x8 b = ((const f16x8*)ldsb)[(kk * 4 + quad) * 128 + t * 16 + n15];
#pragma unroll
      for (int r = 0; r < 2; ++r)
        acc[r][t] = __builtin_amdgcn_mfma_f32_16x16x32_f16(a[r][kk], b, acc[r][t], 0, 0, 0);
    }
  }

  int rbase0 = m0 + quad * 4;
#pragma unroll
  for (int t = 0; t < 8; ++t) {
    float bv = bias[t * 16 + n15];
#pragma unroll
    for (int r = 0; r < 2; ++r) {
#pragma unroll
      for (int i = 0; i < 4; ++i) {
        int row = rbase0 + r * 16 + i;
        if (row < M) {
          float v = acc[r][t][i] + bv;
          if (RELU) v = fmaxf(v, 0.f);
          size_t idx = (size_t)row * 128 + t * 16 + n15;
          if (OUT16) ((f16*)outp)[idx] = (f16)v;
          else       ((float*)outp)[idx] = v;
        }
      }
    }
  }
}

extern "C" void kernel_launch(void* const* d_in, const int* in_sizes, int n_in,
                              void* d_out, int out_size, void* d_ws, size_t ws_size,
                              hipStream_t stream) {
  (void)n_in; (void)out_size; (void)ws_size;
  const float* x    = (const float*)d_in[0];
  const int*   ei   = (const int*)d_in[1];
  const float* W1l  = (const float*)d_in[2];
  const float* b1l  = (const float*)d_in[3];
  const float* W1r  = (const float*)d_in[4];
  const float* W2l  = (const float*)d_in[5];
  const float* b2l  = (const float*)d_in[6];
  const float* W2r  = (const float*)d_in[7];
  const float* Wlin = (const float*)d_in[8];
  const float* blin = (const float*)d_in[9];
  const int N = in_sizes[0] / 128;
  const int E = in_sizes[1] / 2;

  char* ws = (char*)d_ws;
  size_t o = 0;
  auto alloc = [&](size_t bytes) {
    char* p = ws + o;
    o = (o + bytes + 255) & ~(size_t)255;
    return p;
  };
  f16*  xh   = (f16*)alloc((size_t)N * 128 * 2);
  f16*  x1h  = (f16*)alloc((size_t)N * 128 * 2);
  f16*  x2h  = (f16*)alloc((size_t)N * 128 * 2);
  f16*  mh   = (f16*)alloc((size_t)N * 128 * 2);
  f16*  wt   = (f16*)alloc((size_t)3 * 32768 * 2);   // wt1|wt2|wt3 contiguous
  int*  off  = (int*)alloc(((size_t)N + 1) * 4);
  int*  srcs = (int*)alloc((size_t)E * 4);
  u32*  tmp  = (u32*)alloc((size_t)E * 4);           // packed (src<<8)|dstLow
  int*  ghist= (int*)alloc(256 * RNB * 4);
  int*  sg   = (int*)alloc(256 * RNB * 4);
  int*  sums = (int*)alloc(64 * 4);
  f16* wt1 = wt, *wt2 = wt + 32768, *wt3 = wt + 65536;

  const int n4 = N * 128 / 4;
  const int cb = (n4 + 255) / 256;           // convert blocks
  const int wb = (3 * 32768) / 256;          // weight blocks (384)
  const int HB = (N + 255) / 256;            // high-byte buckets (196)
  const int SN = 256 * RNB;                  // scan length 32768
  const int snb = SN / 1024;                 // 32 scan blocks

  // prep (convert + weights + radix hist)
  prep_kernel<<<cb + wb + RNB, 256, 0, stream>>>(x, xh, n4, ei, ghist, E,
                                                 W1l, W1r, W2l, W2r, Wlin, wt, cb, wb);
  // CSR build (atomic-free; chunk prefixes folded into consumers)
  scan_block_kernel<<<snb, 1024, 0, stream>>>(ghist, sg, sums, SN);
  radix_scatter<<<RNB, 256, 0, stream>>>(ei, sg, sums, tmp, E);
  radix_bucket<<<HB, 256, 0, stream>>>(tmp, sg, sums, srcs, off, N, E, HB);

  const int aggBlocks  = ((N + 1) / 2 + 3) / 4;   // 2 nodes/wave, 4 waves/block
  const int gemmBlocks = (N + 127) / 128;         // 128 rows/block

  // layer 1: x1 = relu(mean(x) @ W1_l + x @ W1_r + b1)
  aggregate_kernel<<<aggBlocks, 256, 0, stream>>>(xh, off, srcs, mh, N);
  gemm_kernel<true, true><<<gemmBlocks, 256, 0, stream>>>(mh, xh, wt1, b1l, x1h, N);
  // layer 2: x2 = relu(mean(x1) @ W2_l + x1 @ W2_r + b2)
  aggregate_kernel<<<aggBlocks, 256, 0, stream>>>(x1h, off, srcs, mh, N);
  gemm_kernel<true, true><<<gemmBlocks, 256, 0, stream>>>(mh, x1h, wt2, b2l, x2h, N);
  // head: out = [x1|x2] @ W_lin + b_lin   (fp32 out)
  gemm_kernel<false, false><<<gemmBlocks, 256, 0, stream>>>(x1h, x2h, wt3, blin, d_out, N);
}